// Round 7
// baseline (1845.046 us; speedup 1.0000x reference)
//
#include <hip/hip_runtime.h>
#include <hip/hip_bf16.h>
#include <stdint.h>

#define NSK   1000
#define EMB   256
#define BB    32
#define SS    2048
#define TILE  128
#define NJT   (SS / TILE)             // 16
#define NUNIT (NJT * (NJT + 1) / 2)   // 136 tile-pairs per batch
#define BK    16                      // K-chunk (double-buffered)
#define NCHUNK (EMB / BK)             // 16

typedef __bf16 bf16x8 __attribute__((ext_vector_type(8)));
typedef float  f32x16 __attribute__((ext_vector_type(16)));
typedef float  f32x4  __attribute__((ext_vector_type(4)));

// bf16 table layout in workspace (element offsets)
#define OFF_AI 0                  // alpha_inter  [2000][256]
#define OFF_BI (2 * NSK * EMB)    // beta_inter   [2000][256]
#define OFF_AS (4 * NSK * EMB)    // alpha_skill  [1000][256]
#define OFF_BS (5 * NSK * EMB)    // beta_skill   [1000][256]
#define TOT_BF (6 * NSK * EMB)    // 1,536,000 elements = 3 MB

// convert tables fp32->bf16, zero acc (=d_out) and done counters
__global__ void cvt_tables(const float* __restrict__ ai, const float* __restrict__ bi,
                           const float* __restrict__ as_, const float* __restrict__ bs,
                           __bf16* __restrict__ ws, float* __restrict__ acc,
                           int* __restrict__ done) {
    int i = blockIdx.x * 256 + threadIdx.x;
    if (i < BB * SS) acc[i] = 0.0f;
    if (i < BB * NJT) done[i] = 0;
    if (i >= TOT_BF) return;
    float v;
    if (i < OFF_AS) v = (i < OFF_BI) ? ai[i] : bi[i - OFF_BI];
    else            v = (i < OFF_BS) ? as_[i - OFF_AS] : bs[i - OFF_BS];
    ws[i] = (__bf16)v;
}

// rare duplicate-timestamp rescue: fp32 dot, single code copy (icache)
__device__ __attribute__((noinline)) float dot256(const float* __restrict__ a,
                                                  const float* __restrict__ b) {
    float s = 0.0f;
#pragma unroll 8
    for (int k = 0; k < EMB; ++k) s += a[k] * b[k];
    return s;
}

// one WG = one (b, jt, it) tile-pair; bf16 LDS staging (double-buffered);
// prefetch issued AFTER the barrier so its vmcnt wait lands at WRITEC, not
// at the barrier drain. Fused epilogue via per-(b,jt) done counter.
__global__ __launch_bounds__(256, 4) void hawkes_unit(
    const int* __restrict__ skills, const int* __restrict__ problems,
    const int* __restrict__ times,  const int* __restrict__ labels,
    const __bf16* __restrict__ tab,
    const float* __restrict__ aiW_f, const float* __restrict__ asW_f,
    const float* __restrict__ pbW,   const float* __restrict__ sbW,
    int* __restrict__ done, float* __restrict__ acc)
{
    // double-buffered fragment-order LDS: buf*8192 + mat*2048 + mblk*512 + lane'*8
    __shared__ __align__(16) __bf16 sbuf[2 * 4 * TILE * BK];   // 32 KB
    __shared__ __align__(16) float  t_i[TILE];
    __shared__ __align__(16) float  t_j[TILE];
    __shared__ int   idx_i[TILE];
    __shared__ int   idx_j[TILE];
    __shared__ float colsum[TILE];
    __shared__ int   lastflag;

    const int u  = blockIdx.x;
    const int b  = u / NUNIT;
    const int p  = u - b * NUNIT;
    int jt = (int)((sqrtf(8.0f * (float)p + 1.0f) - 1.0f) * 0.5f);
    while ((jt + 1) * (jt + 2) / 2 <= p) ++jt;
    while (jt * (jt + 1) / 2 > p) --jt;
    const int it   = p - jt * (jt + 1) / 2;
    const bool diag = (it == jt);
    const int j0 = jt * TILE, i0 = it * TILE;

    const int tid = threadIdx.x;
    const int l   = tid & 63;
    const int w   = tid >> 6;
    const int wi  = w >> 1, wj = w & 1;       // 2x2 wave quadrants of 128x128
    const int lane31 = l & 31;
    const int khalf  = l >> 5;

    if (tid < TILE) {
        int j = j0 + tid;
        idx_j[tid] = skills[b * SS + j];
        t_j[tid]   = (float)times[b * SS + j] / 1000.0f;
        colsum[tid] = 0.0f;
    } else {
        int q = tid - TILE;
        int ii = i0 + q;
        idx_i[q] = skills[b * SS + ii] + labels[b * SS + ii] * NSK;
        t_i[q]   = (float)times[b * SS + ii] / 1000.0f;
    }
    __syncthreads();

    const float tj0 = t_j[wj * 64 + lane31];
    const float tj1 = t_j[wj * 64 + 32 + lane31];

    // staging: wave w stages matrix w. lane l: row m*32+(l>>1), 16B half (l&1)
    // (lane pairs coalesce to 32B global segments); frag dest lane' = (l>>1)+32*(l&1).
    const __bf16* my_tab = (w == 0) ? (tab + OFF_AI)
                         : (w == 1) ? (tab + OFF_BI)
                         : (w == 2) ? (tab + OFF_AS)
                         :            (tab + OFF_BS);
    const int* my_idx = (w < 2) ? idx_i : idx_j;
    const __bf16* rowptr[4];
    int wel[4];   // LDS element offset within buffer for this lane's write
#pragma unroll
    for (int m = 0; m < 4; ++m) {
        int r = m * 32 + (l >> 1);
        rowptr[m] = my_tab + (size_t)my_idx[r] * EMB + (l & 1) * 8;
        wel[m] = w * 2048 + m * 512 + ((l >> 1) + 32 * (l & 1)) * 8;
    }

    bf16x8 sreg[4];
#define LOADC(c)                                                    \
    do { _Pragma("unroll")                                          \
        for (int m = 0; m < 4; ++m)                                 \
            sreg[m] = *(const bf16x8*)(rowptr[m] + (c) * BK);       \
    } while (0)
#define WRITEC(buf)                                                 \
    do { _Pragma("unroll")                                          \
        for (int m = 0; m < 4; ++m)                                 \
            *(bf16x8*)(sbuf + (buf) * 8192 + wel[m]) = sreg[m];     \
    } while (0)

    f32x16 accA[2][2], accB[2][2];
#pragma unroll
    for (int mi = 0; mi < 2; ++mi)
#pragma unroll
        for (int nj = 0; nj < 2; ++nj) { accA[mi][nj] = 0.0f; accB[mi][nj] = 0.0f; }

    LOADC(0);
    WRITEC(0);

    for (int c = 0; c < NCHUNK; ++c) {
        const int cur = c & 1;
        __syncthreads();                       // publishes chunk c; vmcnt already 0 here
        if (c + 1 < NCHUNK) LOADC(c + 1);      // issued AFTER barrier: waits at WRITEC only

        const __bf16* sb = sbuf + cur * 8192;
        bf16x8 fa[2], fb[2], ga[2], gb[2];
#pragma unroll
        for (int mi = 0; mi < 2; ++mi) {
            int mb = wi * 2 + mi;
            fa[mi] = *(const bf16x8*)(sb + 0 * 2048 + mb * 512 + l * 8);
            fb[mi] = *(const bf16x8*)(sb + 1 * 2048 + mb * 512 + l * 8);
        }
#pragma unroll
        for (int nj = 0; nj < 2; ++nj) {
            int nb = wj * 2 + nj;
            ga[nj] = *(const bf16x8*)(sb + 2 * 2048 + nb * 512 + l * 8);
            gb[nj] = *(const bf16x8*)(sb + 3 * 2048 + nb * 512 + l * 8);
        }
#pragma unroll
        for (int mi = 0; mi < 2; ++mi)
#pragma unroll
            for (int nj = 0; nj < 2; ++nj) {
                accA[mi][nj] = __builtin_amdgcn_mfma_f32_32x32x16_bf16(fa[mi], ga[nj], accA[mi][nj], 0, 0, 0);
                accB[mi][nj] = __builtin_amdgcn_mfma_f32_32x32x16_bf16(fb[mi], gb[nj], accB[mi][nj], 0, 0, 0);
            }

        if (c + 1 < NCHUNK) WRITEC(cur ^ 1);   // vmcnt wait here, window = reads+MFMAs
    }

    // ---- elementwise + column partial sums ----
    // C/D layout (32x32): col = lane&31, row = (reg&3) + 8*(reg>>2) + 4*(lane>>5)
    float csum0 = 0.0f, csum1 = 0.0f;
#pragma unroll
    for (int mi = 0; mi < 2; ++mi) {
        const int rbase = (wi * 2 + mi) * 32 + 4 * khalf;
        f32x4 tiv[4];
#pragma unroll
        for (int q = 0; q < 4; ++q) tiv[q] = *(const f32x4*)(t_i + rbase + 8 * q);
#pragma unroll
        for (int nj = 0; nj < 2; ++nj) {
            const float tjv = (nj == 0) ? tj0 : tj1;
            const int   jl  = wj * 64 + nj * 32 + lane31;
            float s = 0.0f;
#pragma unroll
            for (int r = 0; r < 16; ++r) {
                const int q = r >> 2, e = r & 3;
                const int il = rbase + 8 * q + e;
                if (diag && il >= jl) continue;   // strict upper triangle (i < j)
                float d = fabsf(tiv[q][e] - tjv);
                float alpha = accA[mi][nj][r];
                if (d == 0.0f)
                    alpha = dot256(aiW_f + (size_t)idx_i[il] * EMB,
                                   asW_f + (size_t)idx_j[jl] * EMB);
                // alpha * exp_nat(-beta*ln(d)/ln5) = alpha * exp2(-beta*log2(d)/ln5)
                float dl   = __builtin_amdgcn_logf(d + 1e-10f) * 0.6213349345596119f;
                float beta = accB[mi][nj][r] + 1.0f;
                beta = fminf(fmaxf(beta, 0.0f), 10.0f);
                s += alpha * __builtin_amdgcn_exp2f(-beta * dl);
            }
            if (nj == 0) csum0 += s; else csum1 += s;
        }
    }

    // ---- reduce to per-column sums, one global atomic per column ----
    __syncthreads();
    csum0 += __shfl_xor(csum0, 32);
    csum1 += __shfl_xor(csum1, 32);
    if (l < 32) {
        atomicAdd(&colsum[wj * 64 + lane31], csum0);
        atomicAdd(&colsum[wj * 64 + 32 + lane31], csum1);
    }
    __syncthreads();
    if (tid < TILE)
        atomicAdd(&acc[b * SS + j0 + tid], colsum[tid]);

    // ---- fused epilogue: last unit of (b,jt) applies bias+sigmoid ----
    // barrier's vmcnt(0) drain = release for ALL waves' acc atomics above
    __syncthreads();
    if (tid == 0) {
        int old = __hip_atomic_fetch_add(&done[b * NJT + jt], 1,
                                         __ATOMIC_ACQ_REL, __HIP_MEMORY_SCOPE_AGENT);
        lastflag = (old == jt);
    }
    __syncthreads();
    if (lastflag && tid < TILE) {
        int j = b * SS + j0 + tid;
        float v = __hip_atomic_load(&acc[j], __ATOMIC_RELAXED, __HIP_MEMORY_SCOPE_AGENT);
        float h = pbW[problems[j]] + sbW[skills[j]] + v;
        acc[j] = 1.0f / (1.0f + __builtin_amdgcn_exp2f(-h * 1.4426950408889634f));
    }
}

extern "C" void kernel_launch(void* const* d_in, const int* in_sizes, int n_in,
                              void* d_out, int out_size, void* d_ws, size_t ws_size,
                              hipStream_t stream) {
    const int*   skills   = (const int*)d_in[0];
    const int*   problems = (const int*)d_in[1];
    const int*   times    = (const int*)d_in[2];
    const int*   labels   = (const int*)d_in[3];
    const float* aiW      = (const float*)d_in[4];  // alpha_inter_W [2000,256]
    const float* asW      = (const float*)d_in[5];  // alpha_skill_W [1000,256]
    const float* biW      = (const float*)d_in[6];  // beta_inter_W  [2000,256]
    const float* bsW      = (const float*)d_in[7];  // beta_skill_W  [1000,256]
    const float* pbW      = (const float*)d_in[8];  // problem_base_W [20000,1]
    const float* sbW      = (const float*)d_in[9];  // skill_base_W   [1000,1]
    float* out = (float*)d_out;                     // doubles as accumulator
    __bf16* tab = (__bf16*)d_ws;                    // 3 MB bf16 tables
    int* done = (int*)((char*)d_ws + TOT_BF * 2);   // 512 counters after table

    cvt_tables<<<(TOT_BF + 255) / 256, 256, 0, stream>>>(aiW, biW, asW, bsW, tab, out, done);
    hawkes_unit<<<BB * NUNIT, 256, 0, stream>>>(skills, problems, times, labels,
                                                tab, aiW, asW, pbW, sbW, done, out);
}

// Round 8
// 334.878 us; speedup vs baseline: 5.5096x; 5.5096x over previous
//
#include <hip/hip_runtime.h>
#include <hip/hip_bf16.h>
#include <stdint.h>

#define NSK   1000
#define EMB   256
#define BB    32
#define SS    2048
#define TILE  128
#define NJT   (SS / TILE)             // 16
#define NUNIT (NJT * (NJT + 1) / 2)   // 136 tile-pairs per batch
#define BK    16                      // K-chunk (double-buffered)
#define NCHUNK (EMB / BK)             // 16

typedef __bf16 bf16x8 __attribute__((ext_vector_type(8)));
typedef float  f32x16 __attribute__((ext_vector_type(16)));
typedef float  f32x4  __attribute__((ext_vector_type(4)));

// bf16 table layout in workspace (element offsets)
#define OFF_AI 0                  // alpha_inter  [2000][256]
#define OFF_BI (2 * NSK * EMB)    // beta_inter   [2000][256]
#define OFF_AS (4 * NSK * EMB)    // alpha_skill  [1000][256]
#define OFF_BS (5 * NSK * EMB)    // beta_skill   [1000][256]
#define TOT_BF (6 * NSK * EMB)    // 1,536,000 elements = 3 MB

// convert tables fp32->bf16, zero acc (=d_out) and done counters
__global__ void cvt_tables(const float* __restrict__ ai, const float* __restrict__ bi,
                           const float* __restrict__ as_, const float* __restrict__ bs,
                           __bf16* __restrict__ ws, float* __restrict__ acc,
                           int* __restrict__ done) {
    int i = blockIdx.x * 256 + threadIdx.x;
    if (i < BB * SS) acc[i] = 0.0f;
    if (i < BB * NJT) done[i] = 0;
    if (i >= TOT_BF) return;
    float v;
    if (i < OFF_AS) v = (i < OFF_BI) ? ai[i] : bi[i - OFF_BI];
    else            v = (i < OFF_BS) ? as_[i - OFF_AS] : bs[i - OFF_BS];
    ws[i] = (__bf16)v;
}

// rare duplicate-timestamp rescue: fp32 dot, single code copy (icache)
__device__ __attribute__((noinline)) float dot256(const float* __restrict__ a,
                                                  const float* __restrict__ b) {
    float s = 0.0f;
#pragma unroll 8
    for (int k = 0; k < EMB; ++k) s += a[k] * b[k];
    return s;
}

// one WG = one (b, jt, it) tile-pair; bf16 LDS staging (double-buffered);
// prefetch issued AFTER the barrier so its vmcnt wait lands at WRITEC.
// Fused epilogue via per-(b,jt) done counter.
// launch_bounds min-waves=2: do NOT raise — (256,4) caps VGPR at 64 and
// spills the 128 accumulator VGPRs to scratch (R6: 7.4 GB HBM, 11x slower).
__global__ __launch_bounds__(256, 2) void hawkes_unit(
    const int* __restrict__ skills, const int* __restrict__ problems,
    const int* __restrict__ times,  const int* __restrict__ labels,
    const __bf16* __restrict__ tab,
    const float* __restrict__ aiW_f, const float* __restrict__ asW_f,
    const float* __restrict__ pbW,   const float* __restrict__ sbW,
    int* __restrict__ done, float* __restrict__ acc)
{
    // double-buffered fragment-order LDS: buf*8192 + mat*2048 + mblk*512 + lane'*8
    __shared__ __align__(16) __bf16 sbuf[2 * 4 * TILE * BK];   // 32 KB
    __shared__ __align__(16) float  t_i[TILE];
    __shared__ __align__(16) float  t_j[TILE];
    __shared__ int   idx_i[TILE];
    __shared__ int   idx_j[TILE];
    __shared__ float colsum[TILE];
    __shared__ int   lastflag;

    const int u  = blockIdx.x;
    const int b  = u / NUNIT;
    const int p  = u - b * NUNIT;
    int jt = (int)((sqrtf(8.0f * (float)p + 1.0f) - 1.0f) * 0.5f);
    while ((jt + 1) * (jt + 2) / 2 <= p) ++jt;
    while (jt * (jt + 1) / 2 > p) --jt;
    const int it   = p - jt * (jt + 1) / 2;
    const bool diag = (it == jt);
    const int j0 = jt * TILE, i0 = it * TILE;

    const int tid = threadIdx.x;
    const int l   = tid & 63;
    const int w   = tid >> 6;
    const int wi  = w >> 1, wj = w & 1;       // 2x2 wave quadrants of 128x128
    const int lane31 = l & 31;
    const int khalf  = l >> 5;

    if (tid < TILE) {
        int j = j0 + tid;
        idx_j[tid] = skills[b * SS + j];
        t_j[tid]   = (float)times[b * SS + j] / 1000.0f;
        colsum[tid] = 0.0f;
    } else {
        int q = tid - TILE;
        int ii = i0 + q;
        idx_i[q] = skills[b * SS + ii] + labels[b * SS + ii] * NSK;
        t_i[q]   = (float)times[b * SS + ii] / 1000.0f;
    }
    __syncthreads();

    const float tj0 = t_j[wj * 64 + lane31];
    const float tj1 = t_j[wj * 64 + 32 + lane31];

    // staging: wave w stages matrix w. lane l: row m*32+(l>>1), 16B half (l&1)
    // (lane pairs coalesce to 32B global segments); frag dest lane' = (l>>1)+32*(l&1).
    const __bf16* my_tab = (w == 0) ? (tab + OFF_AI)
                         : (w == 1) ? (tab + OFF_BI)
                         : (w == 2) ? (tab + OFF_AS)
                         :            (tab + OFF_BS);
    const int* my_idx = (w < 2) ? idx_i : idx_j;
    const __bf16* rowptr[4];
    int wel[4];   // LDS element offset within buffer for this lane's write
#pragma unroll
    for (int m = 0; m < 4; ++m) {
        int r = m * 32 + (l >> 1);
        rowptr[m] = my_tab + (size_t)my_idx[r] * EMB + (l & 1) * 8;
        wel[m] = w * 2048 + m * 512 + ((l >> 1) + 32 * (l & 1)) * 8;
    }

    bf16x8 sreg[4];
#define LOADC(c)                                                    \
    do { _Pragma("unroll")                                          \
        for (int m = 0; m < 4; ++m)                                 \
            sreg[m] = *(const bf16x8*)(rowptr[m] + (c) * BK);       \
    } while (0)
#define WRITEC(buf)                                                 \
    do { _Pragma("unroll")                                          \
        for (int m = 0; m < 4; ++m)                                 \
            *(bf16x8*)(sbuf + (buf) * 8192 + wel[m]) = sreg[m];     \
    } while (0)

    f32x16 accA[2][2], accB[2][2];
#pragma unroll
    for (int mi = 0; mi < 2; ++mi)
#pragma unroll
        for (int nj = 0; nj < 2; ++nj) { accA[mi][nj] = 0.0f; accB[mi][nj] = 0.0f; }

    LOADC(0);
    WRITEC(0);

    for (int c = 0; c < NCHUNK; ++c) {
        const int cur = c & 1;
        __syncthreads();                       // publishes chunk c; vmcnt already 0 here
        if (c + 1 < NCHUNK) LOADC(c + 1);      // issued AFTER barrier: waits at WRITEC only

        const __bf16* sb = sbuf + cur * 8192;
        bf16x8 fa[2], fb[2], ga[2], gb[2];
#pragma unroll
        for (int mi = 0; mi < 2; ++mi) {
            int mb = wi * 2 + mi;
            fa[mi] = *(const bf16x8*)(sb + 0 * 2048 + mb * 512 + l * 8);
            fb[mi] = *(const bf16x8*)(sb + 1 * 2048 + mb * 512 + l * 8);
        }
#pragma unroll
        for (int nj = 0; nj < 2; ++nj) {
            int nb = wj * 2 + nj;
            ga[nj] = *(const bf16x8*)(sb + 2 * 2048 + nb * 512 + l * 8);
            gb[nj] = *(const bf16x8*)(sb + 3 * 2048 + nb * 512 + l * 8);
        }
#pragma unroll
        for (int mi = 0; mi < 2; ++mi)
#pragma unroll
            for (int nj = 0; nj < 2; ++nj) {
                accA[mi][nj] = __builtin_amdgcn_mfma_f32_32x32x16_bf16(fa[mi], ga[nj], accA[mi][nj], 0, 0, 0);
                accB[mi][nj] = __builtin_amdgcn_mfma_f32_32x32x16_bf16(fb[mi], gb[nj], accB[mi][nj], 0, 0, 0);
            }

        if (c + 1 < NCHUNK) WRITEC(cur ^ 1);   // vmcnt wait here, window = reads+MFMAs
    }

    // ---- elementwise + column partial sums ----
    // C/D layout (32x32): col = lane&31, row = (reg&3) + 8*(reg>>2) + 4*(lane>>5)
    float csum0 = 0.0f, csum1 = 0.0f;
#pragma unroll
    for (int mi = 0; mi < 2; ++mi) {
        const int rbase = (wi * 2 + mi) * 32 + 4 * khalf;
        f32x4 tiv[4];
#pragma unroll
        for (int q = 0; q < 4; ++q) tiv[q] = *(const f32x4*)(t_i + rbase + 8 * q);
#pragma unroll
        for (int nj = 0; nj < 2; ++nj) {
            const float tjv = (nj == 0) ? tj0 : tj1;
            const int   jl  = wj * 64 + nj * 32 + lane31;
            float s = 0.0f;
#pragma unroll
            for (int r = 0; r < 16; ++r) {
                const int q = r >> 2, e = r & 3;
                const int il = rbase + 8 * q + e;
                if (diag && il >= jl) continue;   // strict upper triangle (i < j)
                float d = fabsf(tiv[q][e] - tjv);
                float alpha = accA[mi][nj][r];
                if (d == 0.0f)
                    alpha = dot256(aiW_f + (size_t)idx_i[il] * EMB,
                                   asW_f + (size_t)idx_j[jl] * EMB);
                // alpha * exp_nat(-beta*ln(d)/ln5) = alpha * exp2(-beta*log2(d)/ln5)
                float dl   = __builtin_amdgcn_logf(d + 1e-10f) * 0.6213349345596119f;
                float beta = accB[mi][nj][r] + 1.0f;
                beta = fminf(fmaxf(beta, 0.0f), 10.0f);
                s += alpha * __builtin_amdgcn_exp2f(-beta * dl);
            }
            if (nj == 0) csum0 += s; else csum1 += s;
        }
    }

    // ---- reduce to per-column sums, one global atomic per column ----
    __syncthreads();
    csum0 += __shfl_xor(csum0, 32);
    csum1 += __shfl_xor(csum1, 32);
    if (l < 32) {
        atomicAdd(&colsum[wj * 64 + lane31], csum0);
        atomicAdd(&colsum[wj * 64 + 32 + lane31], csum1);
    }
    __syncthreads();
    if (tid < TILE)
        atomicAdd(&acc[b * SS + j0 + tid], colsum[tid]);

    // ---- fused epilogue: last unit of (b,jt) applies bias+sigmoid ----
    __syncthreads();
    if (tid == 0) {
        int old = __hip_atomic_fetch_add(&done[b * NJT + jt], 1,
                                         __ATOMIC_ACQ_REL, __HIP_MEMORY_SCOPE_AGENT);
        lastflag = (old == jt);
    }
    __syncthreads();
    if (lastflag && tid < TILE) {
        int j = b * SS + j0 + tid;
        float v = __hip_atomic_load(&acc[j], __ATOMIC_RELAXED, __HIP_MEMORY_SCOPE_AGENT);
        float h = pbW[problems[j]] + sbW[skills[j]] + v;
        acc[j] = 1.0f / (1.0f + __builtin_amdgcn_exp2f(-h * 1.4426950408889634f));
    }
}

extern "C" void kernel_launch(void* const* d_in, const int* in_sizes, int n_in,
                              void* d_out, int out_size, void* d_ws, size_t ws_size,
                              hipStream_t stream) {
    const int*   skills   = (const int*)d_in[0];
    const int*   problems = (const int*)d_in[1];
    const int*   times    = (const int*)d_in[2];
    const int*   labels   = (const int*)d_in[3];
    const float* aiW      = (const float*)d_in[4];  // alpha_inter_W [2000,256]
    const float* asW      = (const float*)d_in[5];  // alpha_skill_W [1000,256]
    const float* biW      = (const float*)d_in[6];  // beta_inter_W  [2000,256]
    const float* bsW      = (const float*)d_in[7];  // beta_skill_W  [1000,256]
    const float* pbW      = (const float*)d_in[8];  // problem_base_W [20000,1]
    const float* sbW      = (const float*)d_in[9];  // skill_base_W   [1000,1]
    float* out = (float*)d_out;                     // doubles as accumulator
    __bf16* tab = (__bf16*)d_ws;                    // 3 MB bf16 tables
    int* done = (int*)((char*)d_ws + TOT_BF * 2);   // 512 counters after table

    cvt_tables<<<(TOT_BF + 255) / 256, 256, 0, stream>>>(aiW, biW, asW, bsW, tab, out, done);
    hawkes_unit<<<BB * NUNIT, 256, 0, stream>>>(skills, problems, times, labels,
                                                tab, aiW, asW, pbW, sbW, done, out);
}

// Round 9
// 217.320 us; speedup vs baseline: 8.4900x; 1.5409x over previous
//
#include <hip/hip_runtime.h>
#include <hip/hip_bf16.h>
#include <stdint.h>

#define NSK   1000
#define EMB   256
#define BB    32
#define SS    2048
#define TILE  128
#define NJT   (SS / TILE)             // 16
#define NUNIT (NJT * (NJT + 1) / 2)   // 136 tile-pairs per batch
#define BK    16                      // K-chunk (triple-buffered, prefetch dist 2)
#define NCHUNK (EMB / BK)             // 16

typedef __bf16 bf16x8 __attribute__((ext_vector_type(8)));
typedef float  f32x16 __attribute__((ext_vector_type(16)));
typedef float  f32x4  __attribute__((ext_vector_type(4)));

// bf16 table layout in workspace (element offsets)
#define OFF_AI 0                  // alpha_inter  [2000][256]
#define OFF_BI (2 * NSK * EMB)    // beta_inter   [2000][256]
#define OFF_AS (4 * NSK * EMB)    // alpha_skill  [1000][256]
#define OFF_BS (5 * NSK * EMB)    // beta_skill   [1000][256]
#define TOT_BF (6 * NSK * EMB)    // 1,536,000 elements = 3 MB

// convert tables fp32->bf16, zero acc (=d_out)
__global__ void cvt_tables(const float* __restrict__ ai, const float* __restrict__ bi,
                           const float* __restrict__ as_, const float* __restrict__ bs,
                           __bf16* __restrict__ ws, float* __restrict__ acc) {
    int i = blockIdx.x * 256 + threadIdx.x;
    if (i < BB * SS) acc[i] = 0.0f;
    if (i >= TOT_BF) return;
    float v;
    if (i < OFF_AS) v = (i < OFF_BI) ? ai[i] : bi[i - OFF_BI];
    else            v = (i < OFF_BS) ? as_[i - OFF_AS] : bs[i - OFF_BS];
    ws[i] = (__bf16)v;
}

// rare duplicate-timestamp rescue: fp32 dot, single code copy (icache)
__device__ __attribute__((noinline)) float dot256(const float* __restrict__ a,
                                                  const float* __restrict__ b) {
    float s = 0.0f;
#pragma unroll 8
    for (int k = 0; k < EMB; ++k) s += a[k] * b[k];
    return s;
}

// one WG = one (b, jt, it) tile-pair; bf16 LDS staging, TRIPLE-buffered,
// prefetch distance 2: LOADC(c+2) issued before work on chunk c, so the
// WRITEC(c+1) vmcnt wait has a full chunk of slack. Prefetch loads sit
// before the barrier (plain VGPR loads don't drain at s_barrier).
// launch_bounds(256,2): do NOT raise — (256,4) caps VGPR at 64 and spills
// the 128 accumulator regs to scratch (R6: 7.4 GB HBM, 11x slower).
__global__ __launch_bounds__(256, 2) void hawkes_unit(
    const int* __restrict__ skills, const int* __restrict__ times,
    const int* __restrict__ labels, const __bf16* __restrict__ tab,
    const float* __restrict__ aiW_f, const float* __restrict__ asW_f,
    float* __restrict__ acc)
{
    // triple-buffered fragment-order LDS: buf*8192 + mat*2048 + mblk*512 + lane'*8
    __shared__ __align__(16) __bf16 sbuf[3 * 4 * TILE * BK];   // 48 KB
    __shared__ __align__(16) float  t_i[TILE];
    __shared__ __align__(16) float  t_j[TILE];
    __shared__ int   idx_i[TILE];
    __shared__ int   idx_j[TILE];
    __shared__ float colsum[TILE];

    const int u  = blockIdx.x;
    const int b  = u / NUNIT;
    const int p  = u - b * NUNIT;
    int jt = (int)((sqrtf(8.0f * (float)p + 1.0f) - 1.0f) * 0.5f);
    while ((jt + 1) * (jt + 2) / 2 <= p) ++jt;
    while (jt * (jt + 1) / 2 > p) --jt;
    const int it   = p - jt * (jt + 1) / 2;
    const bool diag = (it == jt);
    const int j0 = jt * TILE, i0 = it * TILE;

    const int tid = threadIdx.x;
    const int l   = tid & 63;
    const int w   = tid >> 6;
    const int wi  = w >> 1, wj = w & 1;       // 2x2 wave quadrants of 128x128
    const int lane31 = l & 31;
    const int khalf  = l >> 5;

    if (tid < TILE) {
        int j = j0 + tid;
        idx_j[tid] = skills[b * SS + j];
        t_j[tid]   = (float)times[b * SS + j] / 1000.0f;
        colsum[tid] = 0.0f;
    } else {
        int q = tid - TILE;
        int ii = i0 + q;
        idx_i[q] = skills[b * SS + ii] + labels[b * SS + ii] * NSK;
        t_i[q]   = (float)times[b * SS + ii] / 1000.0f;
    }
    __syncthreads();

    const float tj0 = t_j[wj * 64 + lane31];
    const float tj1 = t_j[wj * 64 + 32 + lane31];

    // staging: wave w stages matrix w. lane l: row m*32+(l>>1), 16B half (l&1)
    // (lane pairs coalesce to 32B global segments); frag dest lane' = (l>>1)+32*(l&1).
    const __bf16* my_tab = (w == 0) ? (tab + OFF_AI)
                         : (w == 1) ? (tab + OFF_BI)
                         : (w == 2) ? (tab + OFF_AS)
                         :            (tab + OFF_BS);
    const int* my_idx = (w < 2) ? idx_i : idx_j;
    const __bf16* rowptr[4];
    int wel[4];   // LDS element offset within buffer for this lane's write
#pragma unroll
    for (int m = 0; m < 4; ++m) {
        int r = m * 32 + (l >> 1);
        rowptr[m] = my_tab + (size_t)my_idx[r] * EMB + (l & 1) * 8;
        wel[m] = w * 2048 + m * 512 + ((l >> 1) + 32 * (l & 1)) * 8;
    }

#define LOADC(dst, c)                                               \
    do { _Pragma("unroll")                                          \
        for (int m = 0; m < 4; ++m)                                 \
            dst[m] = *(const bf16x8*)(rowptr[m] + (c) * BK);        \
    } while (0)
#define WRITEC(src, buf)                                            \
    do { _Pragma("unroll")                                          \
        for (int m = 0; m < 4; ++m)                                 \
            *(bf16x8*)(sbuf + (buf) * 8192 + wel[m]) = src[m];      \
    } while (0)

    f32x16 accA[2][2], accB[2][2];
#pragma unroll
    for (int mi = 0; mi < 2; ++mi)
#pragma unroll
        for (int nj = 0; nj < 2; ++nj) { accA[mi][nj] = 0.0f; accB[mi][nj] = 0.0f; }

    bf16x8 sregA[4], sregB[4];
    LOADC(sregA, 0);
    WRITEC(sregA, 0);        // chunk 0 -> buf 0
    LOADC(sregA, 1);         // chunk 1 staged in regs

    for (int c = 0; c < NCHUNK; ++c) {
        const int cur = c % 3;
        // issue gather for c+2 BEFORE the barrier: its latency overlaps the
        // barrier wait + this whole chunk's compute.
        if (c + 2 < NCHUNK) {
            if (c & 1) LOADC(sregA, c + 2);
            else       LOADC(sregB, c + 2);
        }
        __syncthreads();                       // publishes buf[c%3]

        const __bf16* sb = sbuf + cur * 8192;
        bf16x8 fa[2], fb[2], ga[2], gb[2];
#pragma unroll
        for (int mi = 0; mi < 2; ++mi) {
            int mb = wi * 2 + mi;
            fa[mi] = *(const bf16x8*)(sb + 0 * 2048 + mb * 512 + l * 8);
            fb[mi] = *(const bf16x8*)(sb + 1 * 2048 + mb * 512 + l * 8);
        }
#pragma unroll
        for (int nj = 0; nj < 2; ++nj) {
            int nb = wj * 2 + nj;
            ga[nj] = *(const bf16x8*)(sb + 2 * 2048 + nb * 512 + l * 8);
            gb[nj] = *(const bf16x8*)(sb + 3 * 2048 + nb * 512 + l * 8);
        }
#pragma unroll
        for (int mi = 0; mi < 2; ++mi)
#pragma unroll
            for (int nj = 0; nj < 2; ++nj) {
                accA[mi][nj] = __builtin_amdgcn_mfma_f32_32x32x16_bf16(fa[mi], ga[nj], accA[mi][nj], 0, 0, 0);
                accB[mi][nj] = __builtin_amdgcn_mfma_f32_32x32x16_bf16(fb[mi], gb[nj], accB[mi][nj], 0, 0, 0);
            }

        // write chunk c+1 (loaded a full chunk ago -> vmcnt slack ~1 chunk)
        if (c + 1 < NCHUNK) {
            if (c & 1) WRITEC(sregB, (c + 1) % 3);
            else       WRITEC(sregA, (c + 1) % 3);
        }
    }

    // ---- elementwise + column partial sums ----
    // C/D layout (32x32): col = lane&31, row = (reg&3) + 8*(reg>>2) + 4*(lane>>5)
    float csum0 = 0.0f, csum1 = 0.0f;
#pragma unroll
    for (int mi = 0; mi < 2; ++mi) {
        const int rbase = (wi * 2 + mi) * 32 + 4 * khalf;
        f32x4 tiv[4];
#pragma unroll
        for (int q = 0; q < 4; ++q) tiv[q] = *(const f32x4*)(t_i + rbase + 8 * q);
#pragma unroll
        for (int nj = 0; nj < 2; ++nj) {
            const float tjv = (nj == 0) ? tj0 : tj1;
            const int   jl  = wj * 64 + nj * 32 + lane31;
            float s = 0.0f;
#pragma unroll
            for (int r = 0; r < 16; ++r) {
                const int q = r >> 2, e = r & 3;
                const int il = rbase + 8 * q + e;
                if (diag && il >= jl) continue;   // strict upper triangle (i < j)
                float d = fabsf(tiv[q][e] - tjv);
                float alpha = accA[mi][nj][r];
                if (d == 0.0f)
                    alpha = dot256(aiW_f + (size_t)idx_i[il] * EMB,
                                   asW_f + (size_t)idx_j[jl] * EMB);
                // alpha * exp_nat(-beta*ln(d)/ln5) = alpha * exp2(-beta*log2(d)/ln5)
                float dl   = __builtin_amdgcn_logf(d + 1e-10f) * 0.6213349345596119f;
                float beta = accB[mi][nj][r] + 1.0f;
                beta = fminf(fmaxf(beta, 0.0f), 10.0f);
                s += alpha * __builtin_amdgcn_exp2f(-beta * dl);
            }
            if (nj == 0) csum0 += s; else csum1 += s;
        }
    }

    // ---- reduce to per-column sums, one global atomic per column ----
    __syncthreads();
    csum0 += __shfl_xor(csum0, 32);
    csum1 += __shfl_xor(csum1, 32);
    if (l < 32) {
        atomicAdd(&colsum[wj * 64 + lane31], csum0);
        atomicAdd(&colsum[wj * 64 + 32 + lane31], csum1);
    }
    __syncthreads();
    if (tid < TILE)
        atomicAdd(&acc[b * SS + j0 + tid], colsum[tid]);
}

__global__ void hawkes_final(const int* __restrict__ skills, const int* __restrict__ problems,
                             const float* __restrict__ pbW, const float* __restrict__ sbW,
                             float* __restrict__ out) {
    int i = blockIdx.x * 256 + threadIdx.x;
    if (i >= BB * SS) return;
    float h = pbW[problems[i]] + sbW[skills[i]] + out[i];
    out[i] = 1.0f / (1.0f + __builtin_amdgcn_exp2f(-h * 1.4426950408889634f));
}

extern "C" void kernel_launch(void* const* d_in, const int* in_sizes, int n_in,
                              void* d_out, int out_size, void* d_ws, size_t ws_size,
                              hipStream_t stream) {
    const int*   skills   = (const int*)d_in[0];
    const int*   problems = (const int*)d_in[1];
    const int*   times    = (const int*)d_in[2];
    const int*   labels   = (const int*)d_in[3];
    const float* aiW      = (const float*)d_in[4];  // alpha_inter_W [2000,256]
    const float* asW      = (const float*)d_in[5];  // alpha_skill_W [1000,256]
    const float* biW      = (const float*)d_in[6];  // beta_inter_W  [2000,256]
    const float* bsW      = (const float*)d_in[7];  // beta_skill_W  [1000,256]
    const float* pbW      = (const float*)d_in[8];  // problem_base_W [20000,1]
    const float* sbW      = (const float*)d_in[9];  // skill_base_W   [1000,1]
    float* out = (float*)d_out;                     // doubles as accumulator
    __bf16* tab = (__bf16*)d_ws;                    // 3 MB bf16 tables

    cvt_tables<<<(TOT_BF + 255) / 256, 256, 0, stream>>>(aiW, biW, asW, bsW, tab, out);
    hawkes_unit<<<BB * NUNIT, 256, 0, stream>>>(skills, times, labels, tab, aiW, asW, out);
    hawkes_final<<<(BB * SS + 255) / 256, 256, 0, stream>>>(skills, problems, pbW, sbW, out);
}

// Round 10
// 190.737 us; speedup vs baseline: 9.6733x; 1.1394x over previous
//
#include <hip/hip_runtime.h>
#include <hip/hip_bf16.h>
#include <stdint.h>

#define NSK   1000
#define EMB   256
#define BB    32
#define SS    2048
#define TILE  128
#define NJT   (SS / TILE)             // 16
#define NUNIT (NJT * (NJT + 1) / 2)   // 136 tile-pairs per batch
#define BK    32                      // fp8 bytes per row per chunk (2 k-steps)
#define NCHUNK (EMB / BK)             // 8
#define SCALE_INV (1.0f / 4096.0f)    // undo (x64)^2 fp8 pre-scaling

typedef float f32x16 __attribute__((ext_vector_type(16)));
typedef float f32x4  __attribute__((ext_vector_type(4)));
typedef long  longx2 __attribute__((ext_vector_type(2)));

// fp8 table layout in workspace (byte offsets; 1 B/elem)
#define OFF_AI8 0
#define OFF_BI8 (2 * NSK * EMB)   // 512000
#define OFF_AS8 (4 * NSK * EMB)   // 1024000
#define OFF_BS8 (5 * NSK * EMB)   // 1280000
#define TOT8    (6 * NSK * EMB)   // 1536000 bytes

// convert 4 tables fp32 -> fp8 e4m3 (x64 pre-scale), zero acc (=d_out)
__global__ void cvt_tables(const float* __restrict__ ai, const float* __restrict__ bi,
                           const float* __restrict__ as_, const float* __restrict__ bs,
                           int* __restrict__ ws8, float* __restrict__ acc) {
    int g = blockIdx.x * 256 + threadIdx.x;   // one 4-elem group per thread
    if (g < BB * SS) acc[g] = 0.0f;
    if (g * 4 >= TOT8) return;
    int e = g * 4;
    const float* src; int off;
    if (e < OFF_AS8) { if (e < OFF_BI8) { src = ai;  off = e; }
                       else             { src = bi;  off = e - OFF_BI8; } }
    else             { if (e < OFF_BS8) { src = as_; off = e - OFF_AS8; }
                       else             { src = bs;  off = e - OFF_BS8; } }
    const float4 v = *(const float4*)(src + off);
    int lo = __builtin_amdgcn_cvt_pk_fp8_f32(v.x * 64.0f, v.y * 64.0f, 0, false);
    int wd = __builtin_amdgcn_cvt_pk_fp8_f32(v.z * 64.0f, v.w * 64.0f, lo, true);
    ws8[g] = wd;
}

// rare duplicate-timestamp rescue: fp32 dot, single code copy (icache)
__device__ __attribute__((noinline)) float dot256(const float* __restrict__ a,
                                                  const float* __restrict__ b) {
    float s = 0.0f;
#pragma unroll 8
    for (int k = 0; k < EMB; ++k) s += a[k] * b[k];
    return s;
}

// one WG = one (b, jt, it) tile-pair. fp8 e4m3 staging (halves LDS + L2 byte
// streams vs bf16 — the two co-dominant pipes per R8 accounting), TRIPLE-
// buffered LDS with prefetch distance 2 (R8-verified skeleton), BK=32 fp8
// = 2 k-steps per chunk (barriers halve). No fused epilogue (R7: +120us).
// launch_bounds(256,2): do NOT raise — (256,4) spills the 128 acc regs
// (R6: 7.4 GB HBM scratch traffic, 11x slower).
__global__ __launch_bounds__(256, 2) void hawkes_unit(
    const int* __restrict__ skills, const int* __restrict__ times,
    const int* __restrict__ labels, const unsigned char* __restrict__ tab,
    const float* __restrict__ aiW_f, const float* __restrict__ asW_f,
    const float* __restrict__ biW_f, const float* __restrict__ bsW_f,
    float* __restrict__ acc)
{
    // triple-buffered fragment-order LDS:
    // byte addr = buf*16384 + mat*4096 + mblk*1024 + ks*512 + lane'*8
    __shared__ __align__(16) char  sbuf[3 * 16384];   // 48 KB
    __shared__ __align__(16) float t_i[TILE];
    __shared__ __align__(16) float t_j[TILE];
    __shared__ int   idx_i[TILE];
    __shared__ int   idx_j[TILE];
    __shared__ float colsum[TILE];

    const int u  = blockIdx.x;
    const int b  = u / NUNIT;
    const int p  = u - b * NUNIT;
    int jt = (int)((sqrtf(8.0f * (float)p + 1.0f) - 1.0f) * 0.5f);
    while ((jt + 1) * (jt + 2) / 2 <= p) ++jt;
    while (jt * (jt + 1) / 2 > p) --jt;
    const int it   = p - jt * (jt + 1) / 2;
    const bool diag = (it == jt);
    const int j0 = jt * TILE, i0 = it * TILE;

    const int tid = threadIdx.x;
    const int l   = tid & 63;
    const int w   = tid >> 6;
    const int wi  = w >> 1, wj = w & 1;       // 2x2 wave quadrants of 128x128
    const int lane31 = l & 31;
    const int khalf  = l >> 5;

    if (tid < TILE) {
        int j = j0 + tid;
        idx_j[tid] = skills[b * SS + j];
        t_j[tid]   = (float)times[b * SS + j] / 1000.0f;
        colsum[tid] = 0.0f;
    } else {
        int q = tid - TILE;
        int ii = i0 + q;
        idx_i[q] = skills[b * SS + ii] + labels[b * SS + ii] * NSK;
        t_i[q]   = (float)times[b * SS + ii] / 1000.0f;
    }
    __syncthreads();

    const float tj0 = t_j[wj * 64 + lane31];
    const float tj1 = t_j[wj * 64 + 32 + lane31];

    // staging: wave w stages matrix w. lane l: row r = m*32+(l>>1), 16B piece
    // (l&1) of the row's 32B chunk (= k-step l&1 whole); lane pairs coalesce
    // to 32B global segments. The 16B splits into khalf0 (8B -> frag lane r)
    // and khalf1 (8B -> frag lane 32+r, i.e. +256B).
    const unsigned char* my_tab = tab + ((w == 0) ? OFF_AI8 : (w == 1) ? OFF_BI8
                                       : (w == 2) ? OFF_AS8 : OFF_BS8);
    const int* my_idx = (w < 2) ? idx_i : idx_j;
    const unsigned char* rowptr[4];
    int wo[4];   // LDS byte offset (within buffer) of this lane's khalf0 write
#pragma unroll
    for (int m = 0; m < 4; ++m) {
        int r = m * 32 + (l >> 1);
        rowptr[m] = my_tab + (size_t)my_idx[r] * EMB + (l & 1) * 16;
        wo[m] = w * 4096 + m * 1024 + (l & 1) * 512 + (l >> 1) * 8;
    }

#define LOADC(dst, c)                                                  \
    do { _Pragma("unroll")                                             \
        for (int m = 0; m < 4; ++m)                                    \
            dst[m] = *(const longx2*)(rowptr[m] + (c) * BK);           \
    } while (0)
#define WRITEC(src, buf)                                               \
    do { char* db = sbuf + (buf) * 16384;                              \
        _Pragma("unroll")                                              \
        for (int m = 0; m < 4; ++m) {                                  \
            *(long*)(db + wo[m])       = src[m].x;                     \
            *(long*)(db + wo[m] + 256) = src[m].y;                     \
        }                                                              \
    } while (0)

    f32x16 accA[2][2], accB[2][2];
#pragma unroll
    for (int mi = 0; mi < 2; ++mi)
#pragma unroll
        for (int nj = 0; nj < 2; ++nj) { accA[mi][nj] = 0.0f; accB[mi][nj] = 0.0f; }

    longx2 sregA[4], sregB[4];
    LOADC(sregA, 0);
    WRITEC(sregA, 0);        // chunk 0 -> buf 0
    LOADC(sregA, 1);         // chunk 1 staged in regs

    for (int c = 0; c < NCHUNK; ++c) {
        const int cur = c % 3;
        // gather for c+2 issued BEFORE the barrier: latency overlaps the
        // barrier wait + this whole chunk's compute (plain VGPR loads do
        // not drain at s_barrier).
        if (c + 2 < NCHUNK) {
            if (c & 1) LOADC(sregA, c + 2);
            else       LOADC(sregB, c + 2);
        }
        __syncthreads();                       // publishes buf[c%3]

        const char* sb = sbuf + cur * 16384;
#pragma unroll
        for (int ks = 0; ks < 2; ++ks) {
            long fa[2], fb[2], ga[2], gb[2];
#pragma unroll
            for (int mi = 0; mi < 2; ++mi) {
                int mb = (wi * 2 + mi) * 1024 + ks * 512 + l * 8;
                fa[mi] = *(const long*)(sb + 0    + mb);
                fb[mi] = *(const long*)(sb + 4096 + mb);
            }
#pragma unroll
            for (int nj = 0; nj < 2; ++nj) {
                int nb = (wj * 2 + nj) * 1024 + ks * 512 + l * 8;
                ga[nj] = *(const long*)(sb + 8192  + nb);
                gb[nj] = *(const long*)(sb + 12288 + nb);
            }
#pragma unroll
            for (int mi = 0; mi < 2; ++mi)
#pragma unroll
                for (int nj = 0; nj < 2; ++nj) {
                    accA[mi][nj] = __builtin_amdgcn_mfma_f32_32x32x16_fp8_fp8(
                        fa[mi], ga[nj], accA[mi][nj], 0, 0, 0);
                    accB[mi][nj] = __builtin_amdgcn_mfma_f32_32x32x16_fp8_fp8(
                        fb[mi], gb[nj], accB[mi][nj], 0, 0, 0);
                }
        }

        // write chunk c+1 (loaded a full chunk ago -> vmcnt slack ~1 chunk)
        if (c + 1 < NCHUNK) {
            if (c & 1) WRITEC(sregB, (c + 1) % 3);
            else       WRITEC(sregA, (c + 1) % 3);
        }
    }

    // ---- elementwise + column partial sums ----
    // C/D layout (32x32): col = lane&31, row = (reg&3) + 8*(reg>>2) + 4*(lane>>5)
    // alpha's 1/4096 scale is folded out of the loop (csum *= SCALE_INV at end);
    // rescue values are multiplied by 4096 to stay consistent.
    float csum0 = 0.0f, csum1 = 0.0f;
#pragma unroll
    for (int mi = 0; mi < 2; ++mi) {
        const int rbase = (wi * 2 + mi) * 32 + 4 * khalf;
        f32x4 tiv[4];
#pragma unroll
        for (int q = 0; q < 4; ++q) tiv[q] = *(const f32x4*)(t_i + rbase + 8 * q);
#pragma unroll
        for (int nj = 0; nj < 2; ++nj) {
            const float tjv = (nj == 0) ? tj0 : tj1;
            const int   jl  = wj * 64 + nj * 32 + lane31;
            float s = 0.0f;
#pragma unroll
            for (int r = 0; r < 16; ++r) {
                const int q = r >> 2, e = r & 3;
                const int il = rbase + 8 * q + e;
                if (diag && il >= jl) continue;   // strict upper triangle (i < j)
                float d = fabsf(tiv[q][e] - tjv);
                float alpha, braw;
                if (d == 0.0f) {   // huge kernel weight: fp32 both dots
                    alpha = dot256(aiW_f + (size_t)idx_i[il] * EMB,
                                   asW_f + (size_t)idx_j[jl] * EMB) * 4096.0f;
                    braw  = dot256(biW_f + (size_t)idx_i[il] * EMB,
                                   bsW_f + (size_t)idx_j[jl] * EMB) * 4096.0f;
                } else {
                    alpha = accA[mi][nj][r];
                    braw  = accB[mi][nj][r];
                }
                // alpha * exp_nat(-beta*ln(d)/ln5) = alpha * exp2(-beta*log2(d)/ln5)
                float dl   = __builtin_amdgcn_logf(d + 1e-10f) * 0.6213349345596119f;
                float beta = fminf(fmaxf(braw * SCALE_INV + 1.0f, 0.0f), 10.0f);
                s += alpha * __builtin_amdgcn_exp2f(-beta * dl);
            }
            if (nj == 0) csum0 += s; else csum1 += s;
        }
    }
    csum0 *= SCALE_INV;
    csum1 *= SCALE_INV;

    // ---- reduce to per-column sums, one global atomic per column ----
    __syncthreads();
    csum0 += __shfl_xor(csum0, 32);
    csum1 += __shfl_xor(csum1, 32);
    if (l < 32) {
        atomicAdd(&colsum[wj * 64 + lane31], csum0);
        atomicAdd(&colsum[wj * 64 + 32 + lane31], csum1);
    }
    __syncthreads();
    if (tid < TILE)
        atomicAdd(&acc[b * SS + j0 + tid], colsum[tid]);
}

__global__ void hawkes_final(const int* __restrict__ skills, const int* __restrict__ problems,
                             const float* __restrict__ pbW, const float* __restrict__ sbW,
                             float* __restrict__ out) {
    int i = blockIdx.x * 256 + threadIdx.x;
    if (i >= BB * SS) return;
    float h = pbW[problems[i]] + sbW[skills[i]] + out[i];
    out[i] = 1.0f / (1.0f + __builtin_amdgcn_exp2f(-h * 1.4426950408889634f));
}

extern "C" void kernel_launch(void* const* d_in, const int* in_sizes, int n_in,
                              void* d_out, int out_size, void* d_ws, size_t ws_size,
                              hipStream_t stream) {
    const int*   skills   = (const int*)d_in[0];
    const int*   problems = (const int*)d_in[1];
    const int*   times    = (const int*)d_in[2];
    const int*   labels   = (const int*)d_in[3];
    const float* aiW      = (const float*)d_in[4];  // alpha_inter_W [2000,256]
    const float* asW      = (const float*)d_in[5];  // alpha_skill_W [1000,256]
    const float* biW      = (const float*)d_in[6];  // beta_inter_W  [2000,256]
    const float* bsW      = (const float*)d_in[7];  // beta_skill_W  [1000,256]
    const float* pbW      = (const float*)d_in[8];  // problem_base_W [20000,1]
    const float* sbW      = (const float*)d_in[9];  // skill_base_W   [1000,1]
    float* out = (float*)d_out;                     // doubles as accumulator
    unsigned char* tab = (unsigned char*)d_ws;      // 1.5 MB fp8 tables

    cvt_tables<<<(TOT8 / 4 + 255) / 256, 256, 0, stream>>>(aiW, biW, asW, bsW,
                                                           (int*)tab, out);
    hawkes_unit<<<BB * NUNIT, 256, 0, stream>>>(skills, times, labels, tab,
                                                aiW, asW, biW, bsW, out);
    hawkes_final<<<(BB * SS + 255) / 256, 256, 0, stream>>>(skills, problems, pbW, sbW, out);
}